// Round 11
// baseline (376.844 us; speedup 1.0000x reference)
//
#include <hip/hip_runtime.h>
#include <stdint.h>

// ---------------------------------------------------------------------------
// TransformerBlock for MI355X (gfx950)
// B=2, L=2048, E=1024, H=16, DH=64, FF=4096
// GEMMs: bf16 MFMA 16x16x32, BK=64, XOR-swizzled global_load_lds staging.
//  - MODE 0/2 (QKV, FFN-up): gemm_bt_w — 128x256 tile, 4 waves 2x2
//    (per-wave 64x128: MI=4, NI=8), single-buffer 2-barrier skeleton
//    (R10-proven robust), per-K-half sched_barrier(0) liveness pin
//    (12 frags + 128 acc ~ 190 VGPR < 256 cap; pinning all 24 would spill).
//    1.33x arithmetic intensity, 2x MFMA per barrier vs 128x128.
//  - BN=64 modes (out-proj, FFN-down): gemm_bt_p3 — triple-buffered counted
//    vmcnt (T4), fence-free (unchanged from R10).
// Flash attention v9 (stable 68.8-70.7us, VGPR 48, two contexts): kv-split
// 4-wave blocks, 2-buffer __syncthreads staging, XCD-bijective swizzle,
// 32x32x16 MFMA, kv-permuted V (bits 2<->3), in-register softmax,
// end-of-loop merge. UNTOUCHED.
// d_out is FP32.
// ---------------------------------------------------------------------------

typedef __attribute__((ext_vector_type(8))) short short8;
typedef __attribute__((ext_vector_type(4))) float floatx4;
typedef __attribute__((ext_vector_type(16))) float floatx16;

extern "C" __device__ float __ocml_native_exp2_f32(float);
#define EXP2(x) __ocml_native_exp2_f32(x)

#define MFMA_BF16(a, b, c) __builtin_amdgcn_mfma_f32_16x16x32_bf16((a), (b), (c), 0, 0, 0)
#define MFMA32(a, b, c) __builtin_amdgcn_mfma_f32_32x32x16_bf16((a), (b), (c), 0, 0, 0)

__device__ __forceinline__ unsigned short f2bf(float f) {
  union { float f; unsigned int u; } v; v.f = f;
  unsigned int r = v.u + 0x7FFFu + ((v.u >> 16) & 1u);   // RNE
  return (unsigned short)(r >> 16);
}

__device__ __forceinline__ unsigned int f2u(float f) {
  union { float f; unsigned int u; } v; v.f = f; return v.u;
}

__device__ __forceinline__ short8 pack4(unsigned a, unsigned b, unsigned c, unsigned d) {
  union { unsigned u[4]; short8 s; } v;
  v.u[0] = a; v.u[1] = b; v.u[2] = c; v.u[3] = d;
  return v.s;
}

__device__ __forceinline__ void gl_lds16(const unsigned short* g, unsigned short* l) {
  __builtin_amdgcn_global_load_lds(
      (const __attribute__((address_space(1))) unsigned int*)g,
      (__attribute__((address_space(3))) unsigned int*)l, 16, 0, 0);
}

// ---------------------------------------------------------------------------
// GEMM wide: C[M x N] = A * Bt^T + bias, 128x256 tile, 4 waves 2x2
// (per-wave 64 rows x 128 cols: MI=4, NI=8). Single-buffer 2-barrier.
// LDS rows (64 elem = 8 chunks of 8): chunk' = chunk ^ (row & 7).
// Per K-half: load 4 af + 8 bf, sched_barrier(0) pin (forces 12 frags +
// 128-reg acc live -> blocks the degenerate serialized codegen, R2/R7),
// then 32 MFMAs. Two halves per K-step.
// MODE 0: fused QKV (N=3072): q(bf16, x 8*log2e)/k/v head layout
// MODE 2: bf16 gelu(c), stride 4096               (FFN up)
// ---------------------------------------------------------------------------
template <int MODE>
__global__ __launch_bounds__(256, 2)
void gemm_bt_w(const unsigned short* __restrict__ A,
               const unsigned short* __restrict__ Bt,
               const float* __restrict__ bias,
               void* __restrict__ outp,
               const float* __restrict__ res,
               int K,
               void* __restrict__ out2, void* __restrict__ out3,
               const float* __restrict__ bias2, const float* __restrict__ bias3) {
  constexpr int BM = 128, BN = 256, BK = 64;
  constexpr int MI = 4, NI = 8;
  __shared__ __align__(16) unsigned short As[BM * BK];   // 16 KB
  __shared__ __align__(16) unsigned short Bs[BN * BK];   // 32 KB
  const int tid = threadIdx.x;
  const int wave = tid >> 6, lane = tid & 63, l16 = lane & 15, quad = lane >> 4;
  const int m0 = blockIdx.y * BM, n0 = blockIdx.x * BN;
  const int wm = (wave >> 1) * 64;         // 0 / 64
  const int wn = (wave & 1) * 128;         // 0 / 128
  const int sw = l16 & 7;                  // read-side swizzle (row&7 == l16&7)
  const int sl0 = (quad ^ sw) << 3;        // k-half 0 slot
  const int sl1 = sl0 ^ 32;                // k-half 1 slot

  floatx4 acc[MI][NI] = {};                // 128 VGPR

  for (int k0 = 0; k0 < K; k0 += BK) {
    __syncthreads();
#pragma unroll
    for (int c = 0; c < (BM * BK) / 2048; ++c) {         // A: 4 chunks
      const int e = (c * 256 + tid) * 8;
      const int row = e >> 6, c8 = (e >> 3) & 7;
      gl_lds16(A + (size_t)(m0 + row) * K + k0 + ((c8 ^ (row & 7)) << 3), &As[e]);
    }
#pragma unroll
    for (int c = 0; c < (BN * BK) / 2048; ++c) {         // B: 8 chunks
      const int e = (c * 256 + tid) * 8;
      const int row = e >> 6, c8 = (e >> 3) & 7;
      gl_lds16(Bt + (size_t)(n0 + row) * K + k0 + ((c8 ^ (row & 7)) << 3), &Bs[e]);
    }
    __syncthreads();

    // --- k-half 0 ---
    {
      short8 af[MI], bf[NI];
#pragma unroll
      for (int i = 0; i < MI; ++i)
        af[i] = *(const short8*)&As[(wm + i * 16 + l16) * BK + sl0];
#pragma unroll
      for (int i = 0; i < NI; ++i)
        bf[i] = *(const short8*)&Bs[(wn + i * 16 + l16) * BK + sl0];
      __builtin_amdgcn_sched_barrier(0);   // 12 frags live before MFMAs
#pragma unroll
      for (int mi = 0; mi < MI; ++mi)
#pragma unroll
        for (int ni = 0; ni < NI; ++ni)
          acc[mi][ni] = MFMA_BF16(af[mi], bf[ni], acc[mi][ni]);
    }
    // --- k-half 1 ---
    {
      short8 af[MI], bf[NI];
#pragma unroll
      for (int i = 0; i < MI; ++i)
        af[i] = *(const short8*)&As[(wm + i * 16 + l16) * BK + sl1];
#pragma unroll
      for (int i = 0; i < NI; ++i)
        bf[i] = *(const short8*)&Bs[(wn + i * 16 + l16) * BK + sl1];
      __builtin_amdgcn_sched_barrier(0);
#pragma unroll
      for (int mi = 0; mi < MI; ++mi)
#pragma unroll
        for (int ni = 0; ni < NI; ++ni)
          acc[mi][ni] = MFMA_BF16(af[mi], bf[ni], acc[mi][ni]);
    }
  }

  // epilogue
  const int seg = (MODE == 0) ? (n0 >> 10) : 0;   // block-uniform (256|1024)
  const float* bptr = bias;
  if constexpr (MODE == 0) bptr = (seg == 0) ? bias : (seg == 1 ? bias2 : bias3);

  float bcol[NI];
#pragma unroll
  for (int ni = 0; ni < NI; ++ni) {
    const int n = n0 + wn + ni * 16 + l16;
    bcol[ni] = bptr[(MODE == 0) ? (n & 1023) : n];
  }

#pragma unroll
  for (int mi = 0; mi < MI; ++mi) {
#pragma unroll
    for (int r = 0; r < 4; ++r) {
      const int m = m0 + wm + mi * 16 + quad * 4 + r;
#pragma unroll
      for (int ni = 0; ni < NI; ++ni) {
        const int n = n0 + wn + ni * 16 + l16;
        const float c = acc[mi][ni][r] + bcol[ni];
        if constexpr (MODE == 0) {
          const int b_ = m >> 11, l = m & 2047, hd = n & 1023;
          const size_t idx =
              ((size_t)((b_ * 16 + (hd >> 6)) * 2048 + l)) * 64 + (hd & 63);
          if (seg == 0)       ((unsigned short*)outp)[idx] = f2bf(c * 11.5415603270f);
          else if (seg == 1)  ((unsigned short*)out2)[idx] = f2bf(c);
          else                ((unsigned short*)out3)[idx] = f2bf(c);
        } else {
          const float g = 0.5f * c * (1.0f + erff(c * 0.70710678118654752f));
          ((unsigned short*)outp)[(size_t)m * 4096 + n] = f2bf(g);
        }
      }
    }
  }
}

// ---------------------------------------------------------------------------
// stage helper for the pipelined BN=64 GEMM (lambda-free, R2 lesson).
// 6 gl_lds16 per thread per stage (A: 4 chunks, B: 2 chunks).
// ---------------------------------------------------------------------------
__device__ __forceinline__ void stage_p3(const unsigned short* __restrict__ A,
                                         const unsigned short* __restrict__ Bt,
                                         int K, int m0, int n0, int k0, int tid,
                                         unsigned short* Asb, unsigned short* Bsb) {
#pragma unroll
  for (int c = 0; c < 4; ++c) {            // BM*BK/2048 = 4
    const int e = (c * 256 + tid) * 8;
    const int row = e >> 6, c8 = (e >> 3) & 7;
    gl_lds16(A + (size_t)(m0 + row) * K + k0 + ((c8 ^ (row & 7)) << 3), Asb + e);
  }
#pragma unroll
  for (int c = 0; c < 2; ++c) {            // BN*BK/2048 = 2
    const int e = (c * 256 + tid) * 8;
    const int row = e >> 6, c8 = (e >> 3) & 7;
    gl_lds16(Bt + (size_t)(n0 + row) * K + k0 + ((c8 ^ (row & 7)) << 3), Bsb + e);
  }
}

// ---------------------------------------------------------------------------
// GEMM BN=64, TRIPLE-buffered counted-vmcnt pipeline (T4). out-proj (K=1024)
// and FFN-down (K=4096); both epilogues are fp32 res + c. 4 waves stacked in
// M (32x64 each). Steady state: 3 stages (18 loads) in flight; per K-step
// wait vmcnt(12) = "oldest stage landed", never draining to 0 until the
// tail. barrier AFTER compute guards buffer reuse. Fence-free (R10 state).
// ---------------------------------------------------------------------------
__global__ __launch_bounds__(256)
void gemm_bt_p3(const unsigned short* __restrict__ A,
                const unsigned short* __restrict__ Bt,
                const float* __restrict__ bias,
                float* __restrict__ outp,
                const float* __restrict__ res,
                int K) {
  constexpr int BM = 128, BN = 64, BK = 64, MI = 2, NI = 4;
  __shared__ __align__(16) unsigned short As[3][BM * BK];
  __shared__ __align__(16) unsigned short Bs[3][BN * BK];
  const int tid = threadIdx.x;
  const int wave = tid >> 6, lane = tid & 63, l16 = lane & 15, quad = lane >> 4;
  const int m0 = blockIdx.y * BM, n0 = blockIdx.x * BN;
  const int wm = wave * 32;
  const int sw = l16 & 7;
  const int sl0 = (quad ^ sw) << 3;
  const int sl1 = sl0 ^ 32;

  floatx4 acc[MI][NI] = {};

  const int nt = K / BK;                   // 16 or 64 (always >= 4)
  stage_p3(A, Bt, K, m0, n0, 0 * BK, tid, As[0], Bs[0]);
  stage_p3(A, Bt, K, m0, n0, 1 * BK, tid, As[1], Bs[1]);
  stage_p3(A, Bt, K, m0, n0, 2 * BK, tid, As[2], Bs[2]);

  for (int t = 0; t < nt; ++t) {
    // wait for stage(t) only: 2 newer stages (12 loads) may stay in flight
    if (t < nt - 2)       asm volatile("s_waitcnt vmcnt(12)" ::: "memory");
    else if (t == nt - 2) asm volatile("s_waitcnt vmcnt(6)" ::: "memory");
    else                  asm volatile("s_waitcnt vmcnt(0)" ::: "memory");
    __builtin_amdgcn_s_barrier();          // all waves' stage(t) visible

    const unsigned short* Ab = As[t % 3];
    const unsigned short* Bb = Bs[t % 3];
    short8 af0[MI], af1[MI], bf0[NI], bf1[NI];
#pragma unroll
    for (int i = 0; i < MI; ++i) {
      af0[i] = *(const short8*)&Ab[(wm + i * 16 + l16) * BK + sl0];
      af1[i] = *(const short8*)&Ab[(wm + i * 16 + l16) * BK + sl1];
    }
#pragma unroll
    for (int i = 0; i < NI; ++i) {
      bf0[i] = *(const short8*)&Bb[(i * 16 + l16) * BK + sl0];
      bf1[i] = *(const short8*)&Bb[(i * 16 + l16) * BK + sl1];
    }
#pragma unroll
    for (int mi = 0; mi < MI; ++mi)
#pragma unroll
      for (int ni = 0; ni < NI; ++ni) {
        acc[mi][ni] = MFMA_BF16(af0[mi], bf0[ni], acc[mi][ni]);
        acc[mi][ni] = MFMA_BF16(af1[mi], bf1[ni], acc[mi][ni]);
      }

    __builtin_amdgcn_s_barrier();          // all waves done reading buf[t%3]
    if (t + 3 < nt)
      stage_p3(A, Bt, K, m0, n0, (t + 3) * BK, tid, As[t % 3], Bs[t % 3]);
  }

  float bcol[NI];
#pragma unroll
  for (int ni = 0; ni < NI; ++ni) bcol[ni] = bias[n0 + ni * 16 + l16];

#pragma unroll
  for (int mi = 0; mi < MI; ++mi) {
#pragma unroll
    for (int r = 0; r < 4; ++r) {
      const int m = m0 + wm + mi * 16 + quad * 4 + r;
#pragma unroll
      for (int ni = 0; ni < NI; ++ni) {
        const int n = n0 + ni * 16 + l16;
        const float c = acc[mi][ni][r] + bcol[ni];
        outp[(size_t)m * 1024 + n] = res[(size_t)m * 1024 + n] + c;
      }
    }
  }
}

// ---------------------------------------------------------------------------
// LayerNorm: one block per row of 1024 fp32; bf16 output.
// ---------------------------------------------------------------------------
__global__ __launch_bounds__(256)
void layernorm_kernel(const float* __restrict__ x, const float* __restrict__ w,
                      const float* __restrict__ b, unsigned short* __restrict__ out) {
  const int row = blockIdx.x, tid = threadIdx.x;
  const int wave = tid >> 6, lane = tid & 63;
  const float4 v = ((const float4*)(x + (size_t)row * 1024))[tid];
  float s = v.x + v.y + v.z + v.w;
  float s2 = v.x * v.x + v.y * v.y + v.z * v.z + v.w * v.w;
#pragma unroll
  for (int off = 32; off > 0; off >>= 1) {
    s += __shfl_down(s, off);
    s2 += __shfl_down(s2, off);
  }
  __shared__ float red[8];
  if (lane == 0) { red[wave] = s; red[4 + wave] = s2; }
  __syncthreads();
  const float ts = red[0] + red[1] + red[2] + red[3];
  const float ts2 = red[4] + red[5] + red[6] + red[7];
  const float mu = ts * (1.0f / 1024.0f);
  const float var = ts2 * (1.0f / 1024.0f) - mu * mu;
  const float rs = rsqrtf(var + 1e-5f);
  const float4 wv = ((const float4*)w)[tid];
  const float4 bv = ((const float4*)b)[tid];
  ushort4 o;
  o.x = f2bf((v.x - mu) * rs * wv.x + bv.x);
  o.y = f2bf((v.y - mu) * rs * wv.y + bv.y);
  o.z = f2bf((v.z - mu) * rs * wv.z + bv.z);
  o.w = f2bf((v.w - mu) * rs * wv.w + bv.w);
  ((ushort4*)(out + (size_t)row * 1024))[tid] = o;
}

// ---------------------------------------------------------------------------
// Fused 4-way tiled transpose fp32[1024][1024] -> bf16[1024][1024]^T
// z selects {wq,wk,wv,wo}; dst segments contiguous (wqkvT then woT).
// ---------------------------------------------------------------------------
__global__ __launch_bounds__(256)
void transpose_cast4(const float* __restrict__ s0, const float* __restrict__ s1,
                     const float* __restrict__ s2, const float* __restrict__ s3,
                     unsigned short* __restrict__ dst) {
  __shared__ float tile[32][33];
  const int z = blockIdx.z;
  const float* in = (z == 0) ? s0 : (z == 1) ? s1 : (z == 2) ? s2 : s3;
  unsigned short* out = dst + (size_t)z * 1024 * 1024;
  const int tx = threadIdx.x, ty = threadIdx.y;
  const int c0 = blockIdx.x * 32, r0 = blockIdx.y * 32;
#pragma unroll
  for (int i = 0; i < 4; ++i)
    tile[ty + 8 * i][tx] = in[(size_t)(r0 + ty + 8 * i) * 1024 + c0 + tx];
  __syncthreads();
#pragma unroll
  for (int i = 0; i < 4; ++i)
    out[(size_t)(c0 + ty + 8 * i) * 1024 + r0 + tx] = f2bf(tile[tx][ty + 8 * i]);
}

// Tiled transpose fp32[R][C] -> bf16[C][R]  (wu/wd prep)
__global__ __launch_bounds__(256)
void transpose_cast(const float* __restrict__ in, unsigned short* __restrict__ out,
                    int R, int C) {
  __shared__ float tile[32][33];
  const int tx = threadIdx.x, ty = threadIdx.y;
  const int c0 = blockIdx.x * 32, r0 = blockIdx.y * 32;
#pragma unroll
  for (int i = 0; i < 4; ++i)
    tile[ty + 8 * i][tx] = in[(size_t)(r0 + ty + 8 * i) * C + c0 + tx];
  __syncthreads();
#pragma unroll
  for (int i = 0; i < 4; ++i)
    out[(size_t)(c0 + ty + 8 * i) * R + r0 + tx] = f2bf(tile[tx][ty + 8 * i]);
}

// Tiled transpose bf16[R][C] -> bf16[C][R] per head (z = head index).
// Output column (kv) index gets bits 2<->3 swapped (involution): flash
// consumes V^T with the kv axis permuted so the softmaxed P fragments feed
// the PV MFMA B-operand with no cross-lane exchange.
__global__ __launch_bounds__(256)
void transpose_bf16(const unsigned short* __restrict__ in,
                    unsigned short* __restrict__ out, int R, int C) {
  __shared__ unsigned short tile[32][33];
  const size_t hoff = (size_t)blockIdx.z * R * C;
  in += hoff; out += hoff;
  const int tx = threadIdx.x, ty = threadIdx.y;
  const int c0 = blockIdx.x * 32, r0 = blockIdx.y * 32;
#pragma unroll
  for (int i = 0; i < 4; ++i)
    tile[ty + 8 * i][tx] = in[(size_t)(r0 + ty + 8 * i) * C + c0 + tx];
  __syncthreads();
  const int txp = (tx & ~12) | ((tx & 4) << 1) | ((tx & 8) >> 1);
#pragma unroll
  for (int i = 0; i < 4; ++i)
    out[(size_t)(c0 + ty + 8 * i) * R + r0 + txp] = tile[tx][ty + 8 * i];
}

// ---------------------------------------------------------------------------
// Flash attention v9 (stable; 68.8-70.7us/VGPR48 in two contexts): kv-split
// + XCD-bijective block swizzle. Linear bid -> wg = (bid%8)*128 + bid/8:
// XCD k owns bh [4k,4k+4) x all q-tiles -> 2MB K/V per 4MB L2.
// Block = 4 waves: wave = qw + 2*kw; per KV-tile each wave computes one
// 32x32 S^T tile, 16-reg online softmax (own m,l), partial O over its
// kv-half; halves merged once at the end via LDS overlay. 2-buffer
// __syncthreads staging. UNTOUCHED from R10.
// ---------------------------------------------------------------------------
__global__ __launch_bounds__(256, 4)
void flash_attn(const unsigned short* __restrict__ q,
                const unsigned short* __restrict__ k,
                const unsigned short* __restrict__ v,
                unsigned short* __restrict__ ctx) {
  __shared__ __align__(16) unsigned short Ks[2][64 * 64];   // [kv][dh], swizzled
  __shared__ __align__(16) unsigned short Vs[2][64 * 64];   // [dh][kv'], swizzled
  const int bid = blockIdx.x + (blockIdx.y << 5);           // grid (32,32)
  const int wg = (bid & 7) * 128 + (bid >> 3);              // bijective XCD map
  const int bh = wg >> 5, qt = wg & 31;
  const int tid = threadIdx.x, wave = tid >> 6, lane = tid & 63;
  const int qw = wave & 1, kw = wave >> 1;
  const int lo = lane & 31, hi = lane >> 5, sw7 = lo & 7;
  const unsigned short* kb = k + (size_t)bh * 2048 * 64;
  const unsigned short* vb = v + (size_t)bh * 64 * 2048;

  // Q fragments hoisted: B-operand Q[q=lo][kq*16 + hi*8 + j]
  const int qrow = qt * 64 + qw * 32 + lo;
  const unsigned short* qp = q + ((size_t)bh * 2048 + qrow) * 64;
  short8 qf[4];
#pragma unroll
  for (int kq = 0; kq < 4; ++kq) qf[kq] = *(const short8*)(qp + kq * 16 + hi * 8);

  // t-invariant swizzled chunk offsets (chunk j*2+hi, j=0..3)
  int co[4];
#pragma unroll
  for (int j = 0; j < 4; ++j) co[j] = ((j * 2 + hi) ^ sw7) << 3;

  floatx16 O0 = {}, O1 = {};       // partial O^T[d = 32*(0/1)+crow(r,hi)][q=lo]
  float m_run = -1e30f, l_run = 0.f;

  auto stage = [&](int t, int bufi) {
    const int kv0 = t * 64;
#pragma unroll
    for (int c = 0; c < 2; ++c) {
      const int e = (c * 256 + tid) * 8;
      const int r = e >> 6, ch = (e >> 3) & 7;
      const int sc = ((ch ^ (r & 7)) << 3);
      gl_lds16(kb + (size_t)(kv0 + r) * 64 + sc, &Ks[bufi][e]);
      gl_lds16(vb + (size_t)r * 2048 + kv0 + sc, &Vs[bufi][e]);
    }
  };
  stage(0, 0);

  for (int t = 0; t < 32; ++t) {
    __syncthreads();                 // stage(t) complete; prev-buf reads done
    const int bufi = t & 1;
    if (t + 1 < 32) stage(t + 1, bufi ^ 1);

    const unsigned short* Kb = &Ks[bufi][0];
    const unsigned short* Vb = &Vs[bufi][0];

    // --- S^T (one 32x32 tile: kv 32*kw .. 32*kw+31) ---
    floatx16 st = {};
    __builtin_amdgcn_s_setprio(1);
#pragma unroll
    for (int kq = 0; kq < 4; ++kq) {
      const short8 kf = *(const short8*)&Kb[(kw * 32 + lo) * 64 + co[kq]];
      st = MFMA32(kf, qf[kq], st);
    }
    __builtin_amdgcn_s_setprio(0);

    // --- online softmax over this wave's 16 regs (q = lo fixed) ---
    float mp[4];
#pragma unroll
    for (int r = 0; r < 4; ++r)
      mp[r] = fmaxf(fmaxf(st[r], st[r + 4]), fmaxf(st[r + 8], st[r + 12]));
    float mx = fmaxf(fmaxf(mp[0], mp[1]), fmaxf(mp[2], mp[3]));
    mx = fmaxf(mx, __shfl_xor(mx, 32));
    if (!__all(mx - m_run <= 8.0f)) {       // defer-max: rescale only on growth
      const float m_new = fmaxf(m_run, mx);
      const float alpha = EXP2(m_run - m_new);
      m_run = m_new;
      l_run *= alpha;
#pragma unroll
      for (int r = 0; r < 16; ++r) { O0[r] *= alpha; O1[r] *= alpha; }
    }
#pragma unroll
    for (int r = 0; r < 16; ++r) st[r] = EXP2(st[r] - m_run);   // <= 2^8
    float sp[4];
#pragma unroll
    for (int r = 0; r < 4; ++r)
      sp[r] = (st[r] + st[r + 4]) + (st[r + 8] + st[r + 12]);
    float rsum = (sp[0] + sp[1]) + (sp[2] + sp[3]);
    rsum += __shfl_xor(rsum, 32);
    l_run += rsum;

    // --- pack P: pf[s] = st[8s..8s+7] as bf16 (truncation) ---
    unsigned pw[8];
#pragma unroll
    for (int i = 0; i < 8; ++i)
      pw[i] = __builtin_amdgcn_perm(f2u(st[2 * i + 1]), f2u(st[2 * i]), 0x07060302u);
    const short8 pf0 = pack4(pw[0], pw[1], pw[2], pw[3]);
    const short8 pf1 = pack4(pw[4], pw[5], pw[6], pw[7]);

    // --- partial O^T += V^T . P^T over this kv-half (chunks co[2kw+s]) ---
    __builtin_amdgcn_s_setprio(1);
    {
      const short8 vf00 = *(const short8*)&Vb[lo * 64 + co[2 * kw]];
      const short8 vf01 = *(const short8*)&Vb[(32 + lo) * 64 + co[2 * kw]];
      O0 = MFMA32(vf00, pf0, O0);
      O1 = MFMA32(vf01, pf0, O1);
      const short8 vf10 = *(const short8*)&Vb[lo * 64 + co[2 * kw + 1]];
      const short8 vf11 = *(const short8*)&Vb[(32 + lo) * 64 + co[2 * kw + 1]];
      O0 = MFMA32(vf10, pf1, O0);
      O1 = MFMA32(vf11, pf1, O1);
    }
    __builtin_amdgcn_s_setprio(0);
  }

  // --- merge kv-halves (flash combine), LDS overlaid on Ks/Vs ---
  __syncthreads();                         // all waves done reading K/V LDS
  float* Os = (float*)&Ks[0][0];           // [2][64][32] floats = 16 KB
  float* Ml = (float*)&Vs[0][0];           // m: [0..127], l: [128..255]
  if (kw == 1) {
    float* o = Os + (size_t)(qw * 64 + lane) * 32;
#pragma unroll
    for (int r = 0; r < 16; ++r) {         // rotation keeps banks distinct
      o[(r + lane) & 31] = O0[r];
      o[(16 + r + lane) & 31] = O1[r];
    }
    Ml[qw * 64 + lane] = m_run;
    Ml[128 + qw * 64 + lane] = l_run;
  }
  __syncthreads();
  if (kw == 0) {
    const float m2 = Ml[qw * 64 + lane];
    const float l2 = Ml[128 + qw * 64 + lane];
    const float m = fmaxf(m_run, m2);
    const float a1 = EXP2(m_run - m), a2 = EXP2(m2 - m);
    const float linv = 1.0f / (l_run * a1 + l2 * a2);
    const float* o = Os + (size_t)(qw * 64 + lane) * 32;
    float f0[16], f1[16];
#pragma unroll
    for (int r = 0; r < 16; ++r) {
      f0[r] = (O0[r] * a1 + o[(r + lane) & 31] * a2) * linv;
      f1[r] = (O1[r] * a1 + o[(16 + r + lane) & 31] * a2) * linv;
    }
    const int b_ = bh >> 4, h_ = bh & 15;
    unsigned short* op = ctx + ((size_t)(b_ * 2048) + qrow) * 1024 + h_ * 64;
#pragma unroll
    for (int rq = 0; rq < 4; ++rq) {       // d = rq*8 + hi*4 + ri (+32 for O1)
      ushort4 a4, b4;
      a4.x = f2bf(f0[rq * 4 + 0]); a4.y = f2bf(f0[rq * 4 + 1]);
      a4.z = f2bf(f0[rq * 4 + 2]); a4.w = f2bf(f0[rq * 4 + 3]);
      *(ushort4*)(op + rq * 8 + hi * 4) = a4;
      b4.x = f2bf(f1[rq * 4 + 0]); b4.y = f2bf(f1[rq * 4 + 1]);
      b4.z = f2bf(f1[rq * 4 + 2]); b4.w = f2bf(f1[rq * 4 + 3]);
      *(ushort4*)(op + 32 + rq * 8 + hi * 4) = b4;
    }
  }
}

// ---------------------------------------------------------------------------
// Launch
// ---------------------------------------------------------------------------
extern "C" void kernel_launch(void* const* d_in, const int* in_sizes, int n_in,
                              void* d_out, int out_size, void* d_ws, size_t ws_size,
                              hipStream_t stream) {
  const float* x     = (const float*)d_in[0];
  const float* ln1_w = (const float*)d_in[1];
  const float* ln1_b = (const float*)d_in[2];
  const float* wq    = (const float*)d_in[3];
  const float* bq    = (const float*)d_in[4];
  const float* wk    = (const float*)d_in[5];
  const float* bk    = (const float*)d_in[6];
  const float* wv    = (const float*)d_in[7];
  const float* bv    = (const float*)d_in[8];
  const float* wo    = (const float*)d_in[9];
  const float* bo    = (const float*)d_in[10];
  const float* ln2_w = (const float*)d_in[11];
  const float* ln2_b = (const float*)d_in[12];
  const float* wu    = (const float*)d_in[13];
  const float* bu    = (const float*)d_in[14];
  const float* wd    = (const float*)d_in[15];
  const float* bd    = (const float*)d_in[16];

  char* W = (char*)d_ws;
  const size_t MB = 1ull << 20;
  unsigned short* wqkvT = (unsigned short*)(W + 0 * MB);  // [3072][1024]
  unsigned short* woT   = (unsigned short*)(W + 6 * MB);  // [1024][1024] (contiguous after wqkvT)
  unsigned short* wuT   = (unsigned short*)(W + 8 * MB);  // [4096][1024]
  unsigned short* wdT   = (unsigned short*)(W + 16 * MB); // [1024][4096]
  unsigned short* xn    = (unsigned short*)(W + 24 * MB); // [4096][1024]
  unsigned short* qb    = (unsigned short*)(W + 32 * MB); // [32][2048][64]
  unsigned short* kb    = (unsigned short*)(W + 40 * MB);
  unsigned short* vb    = (unsigned short*)(W + 48 * MB); // [32][64][2048] kv-permuted
  unsigned short* cx    = (unsigned short*)(W + 56 * MB); // vnat -> ctx -> hn
  float*          hid   = (float*)(W + 64 * MB);          // [4096][1024] fp32
  unsigned short* up    = (unsigned short*)(W + 24 * MB); // [4096][4096] (reuse)

  const dim3 tb(32, 8);
  // --- weight prep (bf16, transposed) ---
  transpose_cast4<<<dim3(32, 32, 4), tb, 0, stream>>>(wq, wk, wv, wo, wqkvT);
  transpose_cast<<<dim3(128, 32), tb, 0, stream>>>(wu, wuT, 1024, 4096);
  transpose_cast<<<dim3(32, 128), tb, 0, stream>>>(wd, wdT, 4096, 1024);

  // --- attention block ---
  layernorm_kernel<<<4096, 256, 0, stream>>>(x, ln1_w, ln1_b, xn);
  gemm_bt_w<0><<<dim3(12, 32), 256, 0, stream>>>(
      xn, wqkvT, bq, qb, nullptr, 1024, kb, cx, bk, bv);
  transpose_bf16<<<dim3(2, 64, 32), tb, 0, stream>>>(cx, vb, 2048, 64);
  flash_attn<<<dim3(32, 32), 256, 0, stream>>>(qb, kb, vb, cx);
  gemm_bt_p3<<<dim3(16, 32), 256, 0, stream>>>(
      cx, woT, bo, hid, x, 1024);

  // --- FFN block ---
  layernorm_kernel<<<4096, 256, 0, stream>>>(hid, ln2_w, ln2_b, cx);
  gemm_bt_w<2><<<dim3(16, 32), 256, 0, stream>>>(
      cx, wuT, bu, up, nullptr, 1024, nullptr, nullptr, nullptr, nullptr);
  gemm_bt_p3<<<dim3(16, 32), 256, 0, stream>>>(
      up, wdT, bd, (float*)d_out, hid, 4096);
}

// Round 12
// 375.431 us; speedup vs baseline: 1.0038x; 1.0038x over previous
//
#include <hip/hip_runtime.h>
#include <stdint.h>

// ---------------------------------------------------------------------------
// TransformerBlock for MI355X (gfx950)
// B=2, L=2048, E=1024, H=16, DH=64, FF=4096
// GEMMs: bf16 MFMA 16x16x32, BK=64, XOR-swizzled global_load_lds staging.
//  - MODE 0/2 (QKV, FFN-up): gemm_bt_2b — 128x128 tile (R11: 128x256 was
//    neutral, matching m105 guide data), 2-BUFFER COUNTED-VMCNT pipeline
//    (p3 skeleton, 5-round-verified): {vmcnt(8) -> barrier -> frags+pin ->
//    32 MFMA -> barrier -> stage(t+2)}. Removes the 1-phase drain (stage
//    was drained with zero overlapping compute). 64KB LDS -> 2 blocks/CU.
//    R8-proven sched_barrier(0) liveness pin retained.
//  - BN=64 modes (out-proj, FFN-down): gemm_bt_p3 — triple-buffered counted
//    vmcnt (T4), fence-free (unchanged).
// Flash attention v9 (stable 68.8-71.0us, VGPR 48, three contexts): kv-split
// 4-wave blocks, 2-buffer __syncthreads staging, XCD-bijective swizzle,
// 32x32x16 MFMA, kv-permuted V (bits 2<->3), in-register softmax,
// end-of-loop merge. BYTE-IDENTICAL to R10/R11.
// d_out is FP32.
// ---------------------------------------------------------------------------

typedef __attribute__((ext_vector_type(8))) short short8;
typedef __attribute__((ext_vector_type(4))) float floatx4;
typedef __attribute__((ext_vector_type(16))) float floatx16;

extern "C" __device__ float __ocml_native_exp2_f32(float);
#define EXP2(x) __ocml_native_exp2_f32(x)

#define MFMA_BF16(a, b, c) __builtin_amdgcn_mfma_f32_16x16x32_bf16((a), (b), (c), 0, 0, 0)
#define MFMA32(a, b, c) __builtin_amdgcn_mfma_f32_32x32x16_bf16((a), (b), (c), 0, 0, 0)

__device__ __forceinline__ unsigned short f2bf(float f) {
  union { float f; unsigned int u; } v; v.f = f;
  unsigned int r = v.u + 0x7FFFu + ((v.u >> 16) & 1u);   // RNE
  return (unsigned short)(r >> 16);
}

__device__ __forceinline__ unsigned int f2u(float f) {
  union { float f; unsigned int u; } v; v.f = f; return v.u;
}

__device__ __forceinline__ short8 pack4(unsigned a, unsigned b, unsigned c, unsigned d) {
  union { unsigned u[4]; short8 s; } v;
  v.u[0] = a; v.u[1] = b; v.u[2] = c; v.u[3] = d;
  return v.s;
}

__device__ __forceinline__ void gl_lds16(const unsigned short* g, unsigned short* l) {
  __builtin_amdgcn_global_load_lds(
      (const __attribute__((address_space(1))) unsigned int*)g,
      (__attribute__((address_space(3))) unsigned int*)l, 16, 0, 0);
}

// ---------------------------------------------------------------------------
// stage helper for the 128x128 2-buffer GEMM (lambda-free): 8 gl_lds16 per
// thread per stage (A: 4 chunks, B: 4 chunks). Same XOR swizzle as always:
// LDS rows (64 elem = 8 chunks of 8): chunk' = chunk ^ (row & 7).
// ---------------------------------------------------------------------------
__device__ __forceinline__ void stage_2b(const unsigned short* __restrict__ A,
                                         const unsigned short* __restrict__ Bt,
                                         int K, int m0, int n0, int k0, int tid,
                                         unsigned short* Asb, unsigned short* Bsb) {
#pragma unroll
  for (int c = 0; c < 4; ++c) {            // BM*BK/2048 = 4
    const int e = (c * 256 + tid) * 8;
    const int row = e >> 6, c8 = (e >> 3) & 7;
    gl_lds16(A + (size_t)(m0 + row) * K + k0 + ((c8 ^ (row & 7)) << 3), Asb + e);
  }
#pragma unroll
  for (int c = 0; c < 4; ++c) {            // BN*BK/2048 = 4
    const int e = (c * 256 + tid) * 8;
    const int row = e >> 6, c8 = (e >> 3) & 7;
    gl_lds16(Bt + (size_t)(n0 + row) * K + k0 + ((c8 ^ (row & 7)) << 3), Bsb + e);
  }
}

// ---------------------------------------------------------------------------
// GEMM 128x128, 2-BUFFER COUNTED-VMCNT (p3 skeleton): 4 waves in 2x2
// (64x64 each, MI=4 NI=4). Per K-step: wait vmcnt(8) = "stage(t) landed,
// stage(t+1)'s 8 loads stay in flight" -> barrier -> load 16 frags ->
// sched_barrier(0) pin (R8-proven: blocks the degenerate VGPR=80 serialized
// codegen) -> 32 MFMA -> barrier (buf reuse) -> stage(t+2) into buf t%2.
// MODE 0: fused QKV (N=3072): q(bf16, x 8*log2e)/k/v head layout
// MODE 2: bf16 gelu(c), stride 4096               (FFN up)
// ---------------------------------------------------------------------------
template <int MODE>
__global__ __launch_bounds__(256)
void gemm_bt_2b(const unsigned short* __restrict__ A,
                const unsigned short* __restrict__ Bt,
                const float* __restrict__ bias,
                void* __restrict__ outp,
                const float* __restrict__ res,
                int K,
                void* __restrict__ out2, void* __restrict__ out3,
                const float* __restrict__ bias2, const float* __restrict__ bias3) {
  constexpr int BM = 128, BN = 128, BK = 64;
  constexpr int MI = 4, NI = 4;
  __shared__ __align__(16) unsigned short As[2][BM * BK];   // 2 x 16 KB
  __shared__ __align__(16) unsigned short Bs[2][BN * BK];   // 2 x 16 KB
  const int tid = threadIdx.x;
  const int wave = tid >> 6, lane = tid & 63, l16 = lane & 15, quad = lane >> 4;
  const int m0 = blockIdx.y * BM, n0 = blockIdx.x * BN;
  const int wm = (wave >> 1) * 64;
  const int wn = (wave & 1) * 64;
  const int sw = l16 & 7;                  // read-side swizzle (row&7 == l16&7)
  const int sl0 = (quad ^ sw) << 3;        // k-half 0 slot
  const int sl1 = sl0 ^ 32;                // k-half 1 slot

  floatx4 acc[MI][NI] = {};

  const int nt = K / BK;                   // 16
  stage_2b(A, Bt, K, m0, n0, 0 * BK, tid, As[0], Bs[0]);
  stage_2b(A, Bt, K, m0, n0, 1 * BK, tid, As[1], Bs[1]);

  for (int t = 0; t < nt; ++t) {
    // wait for stage(t) only: the newer stage's 8 loads stay in flight
    if (t < nt - 1) asm volatile("s_waitcnt vmcnt(8)" ::: "memory");
    else            asm volatile("s_waitcnt vmcnt(0)" ::: "memory");
    __builtin_amdgcn_s_barrier();          // all waves' stage(t) visible

    const unsigned short* Ab = As[t & 1];
    const unsigned short* Bb = Bs[t & 1];
    short8 af0[MI], af1[MI], bf0[NI], bf1[NI];
#pragma unroll
    for (int i = 0; i < MI; ++i) {
      af0[i] = *(const short8*)&Ab[(wm + i * 16 + l16) * BK + sl0];
      af1[i] = *(const short8*)&Ab[(wm + i * 16 + l16) * BK + sl1];
    }
#pragma unroll
    for (int i = 0; i < NI; ++i) {
      bf0[i] = *(const short8*)&Bb[(wn + i * 16 + l16) * BK + sl0];
      bf1[i] = *(const short8*)&Bb[(wn + i * 16 + l16) * BK + sl1];
    }
    // Pin: all 16 fragments live before any MFMA (R2/R7 pathology blocker).
    __builtin_amdgcn_sched_barrier(0);
#pragma unroll
    for (int mi = 0; mi < MI; ++mi)
#pragma unroll
      for (int ni = 0; ni < NI; ++ni) {
        acc[mi][ni] = MFMA_BF16(af0[mi], bf0[ni], acc[mi][ni]);
        acc[mi][ni] = MFMA_BF16(af1[mi], bf1[ni], acc[mi][ni]);
      }

    __builtin_amdgcn_s_barrier();          // all waves done reading buf t&1
    if (t + 2 < nt)
      stage_2b(A, Bt, K, m0, n0, (t + 2) * BK, tid, As[t & 1], Bs[t & 1]);
  }

  // epilogue (identical to the proven gemm_bt)
  const int seg = (MODE == 0) ? (n0 >> 10) : 0;   // block-uniform for BN=128
  const float* bptr = bias;
  if constexpr (MODE == 0) bptr = (seg == 0) ? bias : (seg == 1 ? bias2 : bias3);

  float bcol[NI];
#pragma unroll
  for (int ni = 0; ni < NI; ++ni) {
    const int n = n0 + wn + ni * 16 + l16;
    bcol[ni] = bptr[(MODE == 0) ? (n & 1023) : n];
  }

#pragma unroll
  for (int mi = 0; mi < MI; ++mi) {
#pragma unroll
    for (int r = 0; r < 4; ++r) {
      const int m = m0 + wm + mi * 16 + quad * 4 + r;
#pragma unroll
      for (int ni = 0; ni < NI; ++ni) {
        const int n = n0 + wn + ni * 16 + l16;
        const float c = acc[mi][ni][r] + bcol[ni];
        if constexpr (MODE == 0) {
          const int b_ = m >> 11, l = m & 2047, hd = n & 1023;
          const size_t idx =
              ((size_t)((b_ * 16 + (hd >> 6)) * 2048 + l)) * 64 + (hd & 63);
          if (seg == 0)       ((unsigned short*)outp)[idx] = f2bf(c * 11.5415603270f);
          else if (seg == 1)  ((unsigned short*)out2)[idx] = f2bf(c);
          else                ((unsigned short*)out3)[idx] = f2bf(c);
        } else {
          const float g = 0.5f * c * (1.0f + erff(c * 0.70710678118654752f));
          ((unsigned short*)outp)[(size_t)m * 4096 + n] = f2bf(g);
        }
      }
    }
  }
}

// ---------------------------------------------------------------------------
// stage helper for the pipelined BN=64 GEMM (lambda-free, R2 lesson).
// 6 gl_lds16 per thread per stage (A: 4 chunks, B: 2 chunks).
// ---------------------------------------------------------------------------
__device__ __forceinline__ void stage_p3(const unsigned short* __restrict__ A,
                                         const unsigned short* __restrict__ Bt,
                                         int K, int m0, int n0, int k0, int tid,
                                         unsigned short* Asb, unsigned short* Bsb) {
#pragma unroll
  for (int c = 0; c < 4; ++c) {            // BM*BK/2048 = 4
    const int e = (c * 256 + tid) * 8;
    const int row = e >> 6, c8 = (e >> 3) & 7;
    gl_lds16(A + (size_t)(m0 + row) * K + k0 + ((c8 ^ (row & 7)) << 3), Asb + e);
  }
#pragma unroll
  for (int c = 0; c < 2; ++c) {            // BN*BK/2048 = 2
    const int e = (c * 256 + tid) * 8;
    const int row = e >> 6, c8 = (e >> 3) & 7;
    gl_lds16(Bt + (size_t)(n0 + row) * K + k0 + ((c8 ^ (row & 7)) << 3), Bsb + e);
  }
}

// ---------------------------------------------------------------------------
// GEMM BN=64, TRIPLE-buffered counted-vmcnt pipeline (T4). out-proj (K=1024)
// and FFN-down (K=4096); both epilogues are fp32 res + c. 4 waves stacked in
// M (32x64 each). Steady state: 3 stages (18 loads) in flight; per K-step
// wait vmcnt(12) = "oldest stage landed", never draining to 0 until the
// tail. barrier AFTER compute guards buffer reuse. Fence-free (R10 state).
// ---------------------------------------------------------------------------
__global__ __launch_bounds__(256)
void gemm_bt_p3(const unsigned short* __restrict__ A,
                const unsigned short* __restrict__ Bt,
                const float* __restrict__ bias,
                float* __restrict__ outp,
                const float* __restrict__ res,
                int K) {
  constexpr int BM = 128, BN = 64, BK = 64, MI = 2, NI = 4;
  __shared__ __align__(16) unsigned short As[3][BM * BK];
  __shared__ __align__(16) unsigned short Bs[3][BN * BK];
  const int tid = threadIdx.x;
  const int wave = tid >> 6, lane = tid & 63, l16 = lane & 15, quad = lane >> 4;
  const int m0 = blockIdx.y * BM, n0 = blockIdx.x * BN;
  const int wm = wave * 32;
  const int sw = l16 & 7;
  const int sl0 = (quad ^ sw) << 3;
  const int sl1 = sl0 ^ 32;

  floatx4 acc[MI][NI] = {};

  const int nt = K / BK;                   // 16 or 64 (always >= 4)
  stage_p3(A, Bt, K, m0, n0, 0 * BK, tid, As[0], Bs[0]);
  stage_p3(A, Bt, K, m0, n0, 1 * BK, tid, As[1], Bs[1]);
  stage_p3(A, Bt, K, m0, n0, 2 * BK, tid, As[2], Bs[2]);

  for (int t = 0; t < nt; ++t) {
    // wait for stage(t) only: 2 newer stages (12 loads) may stay in flight
    if (t < nt - 2)       asm volatile("s_waitcnt vmcnt(12)" ::: "memory");
    else if (t == nt - 2) asm volatile("s_waitcnt vmcnt(6)" ::: "memory");
    else                  asm volatile("s_waitcnt vmcnt(0)" ::: "memory");
    __builtin_amdgcn_s_barrier();          // all waves' stage(t) visible

    const unsigned short* Ab = As[t % 3];
    const unsigned short* Bb = Bs[t % 3];
    short8 af0[MI], af1[MI], bf0[NI], bf1[NI];
#pragma unroll
    for (int i = 0; i < MI; ++i) {
      af0[i] = *(const short8*)&Ab[(wm + i * 16 + l16) * BK + sl0];
      af1[i] = *(const short8*)&Ab[(wm + i * 16 + l16) * BK + sl1];
    }
#pragma unroll
    for (int i = 0; i < NI; ++i) {
      bf0[i] = *(const short8*)&Bb[(i * 16 + l16) * BK + sl0];
      bf1[i] = *(const short8*)&Bb[(i * 16 + l16) * BK + sl1];
    }
#pragma unroll
    for (int mi = 0; mi < MI; ++mi)
#pragma unroll
      for (int ni = 0; ni < NI; ++ni) {
        acc[mi][ni] = MFMA_BF16(af0[mi], bf0[ni], acc[mi][ni]);
        acc[mi][ni] = MFMA_BF16(af1[mi], bf1[ni], acc[mi][ni]);
      }

    __builtin_amdgcn_s_barrier();          // all waves done reading buf[t%3]
    if (t + 3 < nt)
      stage_p3(A, Bt, K, m0, n0, (t + 3) * BK, tid, As[t % 3], Bs[t % 3]);
  }

  float bcol[NI];
#pragma unroll
  for (int ni = 0; ni < NI; ++ni) bcol[ni] = bias[n0 + ni * 16 + l16];

#pragma unroll
  for (int mi = 0; mi < MI; ++mi) {
#pragma unroll
    for (int r = 0; r < 4; ++r) {
      const int m = m0 + wm + mi * 16 + quad * 4 + r;
#pragma unroll
      for (int ni = 0; ni < NI; ++ni) {
        const int n = n0 + ni * 16 + l16;
        const float c = acc[mi][ni][r] + bcol[ni];
        outp[(size_t)m * 1024 + n] = res[(size_t)m * 1024 + n] + c;
      }
    }
  }
}

// ---------------------------------------------------------------------------
// LayerNorm: one block per row of 1024 fp32; bf16 output.
// ---------------------------------------------------------------------------
__global__ __launch_bounds__(256)
void layernorm_kernel(const float* __restrict__ x, const float* __restrict__ w,
                      const float* __restrict__ b, unsigned short* __restrict__ out) {
  const int row = blockIdx.x, tid = threadIdx.x;
  const int wave = tid >> 6, lane = tid & 63;
  const float4 v = ((const float4*)(x + (size_t)row * 1024))[tid];
  float s = v.x + v.y + v.z + v.w;
  float s2 = v.x * v.x + v.y * v.y + v.z * v.z + v.w * v.w;
#pragma unroll
  for (int off = 32; off > 0; off >>= 1) {
    s += __shfl_down(s, off);
    s2 += __shfl_down(s2, off);
  }
  __shared__ float red[8];
  if (lane == 0) { red[wave] = s; red[4 + wave] = s2; }
  __syncthreads();
  const float ts = red[0] + red[1] + red[2] + red[3];
  const float ts2 = red[4] + red[5] + red[6] + red[7];
  const float mu = ts * (1.0f / 1024.0f);
  const float var = ts2 * (1.0f / 1024.0f) - mu * mu;
  const float rs = rsqrtf(var + 1e-5f);
  const float4 wv = ((const float4*)w)[tid];
  const float4 bv = ((const float4*)b)[tid];
  ushort4 o;
  o.x = f2bf((v.x - mu) * rs * wv.x + bv.x);
  o.y = f2bf((v.y - mu) * rs * wv.y + bv.y);
  o.z = f2bf((v.z - mu) * rs * wv.z + bv.z);
  o.w = f2bf((v.w - mu) * rs * wv.w + bv.w);
  ((ushort4*)(out + (size_t)row * 1024))[tid] = o;
}

// ---------------------------------------------------------------------------
// Fused 4-way tiled transpose fp32[1024][1024] -> bf16[1024][1024]^T
// z selects {wq,wk,wv,wo}; dst segments contiguous (wqkvT then woT).
// ---------------------------------------------------------------------------
__global__ __launch_bounds__(256)
void transpose_cast4(const float* __restrict__ s0, const float* __restrict__ s1,
                     const float* __restrict__ s2, const float* __restrict__ s3,
                     unsigned short* __restrict__ dst) {
  __shared__ float tile[32][33];
  const int z = blockIdx.z;
  const float* in = (z == 0) ? s0 : (z == 1) ? s1 : (z == 2) ? s2 : s3;
  unsigned short* out = dst + (size_t)z * 1024 * 1024;
  const int tx = threadIdx.x, ty = threadIdx.y;
  const int c0 = blockIdx.x * 32, r0 = blockIdx.y * 32;
#pragma unroll
  for (int i = 0; i < 4; ++i)
    tile[ty + 8 * i][tx] = in[(size_t)(r0 + ty + 8 * i) * 1024 + c0 + tx];
  __syncthreads();
#pragma unroll
  for (int i = 0; i < 4; ++i)
    out[(size_t)(c0 + ty + 8 * i) * 1024 + r0 + tx] = f2bf(tile[tx][ty + 8 * i]);
}

// Tiled transpose fp32[R][C] -> bf16[C][R]  (wu/wd prep)
__global__ __launch_bounds__(256)
void transpose_cast(const float* __restrict__ in, unsigned short* __restrict__ out,
                    int R, int C) {
  __shared__ float tile[32][33];
  const int tx = threadIdx.x, ty = threadIdx.y;
  const int c0 = blockIdx.x * 32, r0 = blockIdx.y * 32;
#pragma unroll
  for (int i = 0; i < 4; ++i)
    tile[ty + 8 * i][tx] = in[(size_t)(r0 + ty + 8 * i) * C + c0 + tx];
  __syncthreads();
#pragma unroll
  for (int i = 0; i < 4; ++i)
    out[(size_t)(c0 + ty + 8 * i) * R + r0 + tx] = f2bf(tile[tx][ty + 8 * i]);
}

// Tiled transpose bf16[R][C] -> bf16[C][R] per head (z = head index).
// Output column (kv) index gets bits 2<->3 swapped (involution): flash
// consumes V^T with the kv axis permuted so the softmaxed P fragments feed
// the PV MFMA B-operand with no cross-lane exchange.
__global__ __launch_bounds__(256)
void transpose_bf16(const unsigned short* __restrict__ in,
                    unsigned short* __restrict__ out, int R, int C) {
  __shared__ unsigned short tile[32][33];
  const size_t hoff = (size_t)blockIdx.z * R * C;
  in += hoff; out += hoff;
  const int tx = threadIdx.x, ty = threadIdx.y;
  const int c0 = blockIdx.x * 32, r0 = blockIdx.y * 32;
#pragma unroll
  for (int i = 0; i < 4; ++i)
    tile[ty + 8 * i][tx] = in[(size_t)(r0 + ty + 8 * i) * C + c0 + tx];
  __syncthreads();
  const int txp = (tx & ~12) | ((tx & 4) << 1) | ((tx & 8) >> 1);
#pragma unroll
  for (int i = 0; i < 4; ++i)
    out[(size_t)(c0 + ty + 8 * i) * R + r0 + txp] = tile[tx][ty + 8 * i];
}

// ---------------------------------------------------------------------------
// Flash attention v9 (stable; 68.8-71.0us/VGPR48 in three contexts): kv-split
// + XCD-bijective block swizzle. Linear bid -> wg = (bid%8)*128 + bid/8:
// XCD k owns bh [4k,4k+4) x all q-tiles -> 2MB K/V per 4MB L2.
// Block = 4 waves: wave = qw + 2*kw; per KV-tile each wave computes one
// 32x32 S^T tile, 16-reg online softmax (own m,l), partial O over its
// kv-half; halves merged once at the end via LDS overlay. 2-buffer
// __syncthreads staging. BYTE-IDENTICAL to R10/R11.
// ---------------------------------------------------------------------------
__global__ __launch_bounds__(256, 4)
void flash_attn(const unsigned short* __restrict__ q,
                const unsigned short* __restrict__ k,
                const unsigned short* __restrict__ v,
                unsigned short* __restrict__ ctx) {
  __shared__ __align__(16) unsigned short Ks[2][64 * 64];   // [kv][dh], swizzled
  __shared__ __align__(16) unsigned short Vs[2][64 * 64];   // [dh][kv'], swizzled
  const int bid = blockIdx.x + (blockIdx.y << 5);           // grid (32,32)
  const int wg = (bid & 7) * 128 + (bid >> 3);              // bijective XCD map
  const int bh = wg >> 5, qt = wg & 31;
  const int tid = threadIdx.x, wave = tid >> 6, lane = tid & 63;
  const int qw = wave & 1, kw = wave >> 1;
  const int lo = lane & 31, hi = lane >> 5, sw7 = lo & 7;
  const unsigned short* kb = k + (size_t)bh * 2048 * 64;
  const unsigned short* vb = v + (size_t)bh * 64 * 2048;

  // Q fragments hoisted: B-operand Q[q=lo][kq*16 + hi*8 + j]
  const int qrow = qt * 64 + qw * 32 + lo;
  const unsigned short* qp = q + ((size_t)bh * 2048 + qrow) * 64;
  short8 qf[4];
#pragma unroll
  for (int kq = 0; kq < 4; ++kq) qf[kq] = *(const short8*)(qp + kq * 16 + hi * 8);

  // t-invariant swizzled chunk offsets (chunk j*2+hi, j=0..3)
  int co[4];
#pragma unroll
  for (int j = 0; j < 4; ++j) co[j] = ((j * 2 + hi) ^ sw7) << 3;

  floatx16 O0 = {}, O1 = {};       // partial O^T[d = 32*(0/1)+crow(r,hi)][q=lo]
  float m_run = -1e30f, l_run = 0.f;

  auto stage = [&](int t, int bufi) {
    const int kv0 = t * 64;
#pragma unroll
    for (int c = 0; c < 2; ++c) {
      const int e = (c * 256 + tid) * 8;
      const int r = e >> 6, ch = (e >> 3) & 7;
      const int sc = ((ch ^ (r & 7)) << 3);
      gl_lds16(kb + (size_t)(kv0 + r) * 64 + sc, &Ks[bufi][e]);
      gl_lds16(vb + (size_t)r * 2048 + kv0 + sc, &Vs[bufi][e]);
    }
  };
  stage(0, 0);

  for (int t = 0; t < 32; ++t) {
    __syncthreads();                 // stage(t) complete; prev-buf reads done
    const int bufi = t & 1;
    if (t + 1 < 32) stage(t + 1, bufi ^ 1);

    const unsigned short* Kb = &Ks[bufi][0];
    const unsigned short* Vb = &Vs[bufi][0];

    // --- S^T (one 32x32 tile: kv 32*kw .. 32*kw+31) ---
    floatx16 st = {};
    __builtin_amdgcn_s_setprio(1);
#pragma unroll
    for (int kq = 0; kq < 4; ++kq) {
      const short8 kf = *(const short8*)&Kb[(kw * 32 + lo) * 64 + co[kq]];
      st = MFMA32(kf, qf[kq], st);
    }
    __builtin_amdgcn_s_setprio(0);

    // --- online softmax over this wave's 16 regs (q = lo fixed) ---
    float mp[4];
#pragma unroll
    for (int r = 0; r < 4; ++r)
      mp[r] = fmaxf(fmaxf(st[r], st[r + 4]), fmaxf(st[r + 8], st[r + 12]));
    float mx = fmaxf(fmaxf(mp[0], mp[1]), fmaxf(mp[2], mp[3]));
    mx = fmaxf(mx, __shfl_xor(mx, 32));
    if (!__all(mx - m_run <= 8.0f)) {       // defer-max: rescale only on growth
      const float m_new = fmaxf(m_run, mx);
      const float alpha = EXP2(m_run - m_new);
      m_run = m_new;
      l_run *= alpha;
#pragma unroll
      for (int r = 0; r < 16; ++r) { O0[r] *= alpha; O1[r] *= alpha; }
    }
#pragma unroll
    for (int r = 0; r < 16; ++r) st[r] = EXP2(st[r] - m_run);   // <= 2^8
    float sp[4];
#pragma unroll
    for (int r = 0; r < 4; ++r)
      sp[r] = (st[r] + st[r + 4]) + (st[r + 8] + st[r + 12]);
    float rsum = (sp[0] + sp[1]) + (sp[2] + sp[3]);
    rsum += __shfl_xor(rsum, 32);
    l_run += rsum;

    // --- pack P: pf[s] = st[8s..8s+7] as bf16 (truncation) ---
    unsigned pw[8];
#pragma unroll
    for (int i = 0; i < 8; ++i)
      pw[i] = __builtin_amdgcn_perm(f2u(st[2 * i + 1]), f2u(st[2 * i]), 0x07060302u);
    const short8 pf0 = pack4(pw[0], pw[1], pw[2], pw[3]);
    const short8 pf1 = pack4(pw[4], pw[5], pw[6], pw[7]);

    // --- partial O^T += V^T . P^T over this kv-half (chunks co[2kw+s]) ---
    __builtin_amdgcn_s_setprio(1);
    {
      const short8 vf00 = *(const short8*)&Vb[lo * 64 + co[2 * kw]];
      const short8 vf01 = *(const short8*)&Vb[(32 + lo) * 64 + co[2 * kw]];
      O0 = MFMA32(vf00, pf0, O0);
      O1 = MFMA32(vf01, pf0, O1);
      const short8 vf10 = *(const short8*)&Vb[lo * 64 + co[2 * kw + 1]];
      const short8 vf11 = *(const short8*)&Vb[(32 + lo) * 64 + co[2 * kw + 1]];
      O0 = MFMA32(vf10, pf1, O0);
      O1 = MFMA32(vf11, pf1, O1);
    }
    __builtin_amdgcn_s_setprio(0);
  }

  // --- merge kv-halves (flash combine), LDS overlaid on Ks/Vs ---
  __syncthreads();                         // all waves done reading K/V LDS
  float* Os = (float*)&Ks[0][0];           // [2][64][32] floats = 16 KB
  float* Ml = (float*)&Vs[0][0];           // m: [0..127], l: [128..255]
  if (kw == 1) {
    float* o = Os + (size_t)(qw * 64 + lane) * 32;
#pragma unroll
    for (int r = 0; r < 16; ++r) {         // rotation keeps banks distinct
      o[(r + lane) & 31] = O0[r];
      o[(16 + r + lane) & 31] = O1[r];
    }
    Ml[qw * 64 + lane] = m_run;
    Ml[128 + qw * 64 + lane] = l_run;
  }
  __syncthreads();
  if (kw == 0) {
    const float m2 = Ml[qw * 64 + lane];
    const float l2 = Ml[128 + qw * 64 + lane];
    const float m = fmaxf(m_run, m2);
    const float a1 = EXP2(m_run - m), a2 = EXP2(m2 - m);
    const float linv = 1.0f / (l_run * a1 + l2 * a2);
    const float* o = Os + (size_t)(qw * 64 + lane) * 32;
    float f0[16], f1[16];
#pragma unroll
    for (int r = 0; r < 16; ++r) {
      f0[r] = (O0[r] * a1 + o[(r + lane) & 31] * a2) * linv;
      f1[r] = (O1[r] * a1 + o[(16 + r + lane) & 31] * a2) * linv;
    }
    const int b_ = bh >> 4, h_ = bh & 15;
    unsigned short* op = ctx + ((size_t)(b_ * 2048) + qrow) * 1024 + h_ * 64;
#pragma unroll
    for (int rq = 0; rq < 4; ++rq) {       // d = rq*8 + hi*4 + ri (+32 for O1)
      ushort4 a4, b4;
      a4.x = f2bf(f0[rq * 4 + 0]); a4.y = f2bf(f0[rq * 4 + 1]);
      a4.z = f2bf(f0[rq * 4 + 2]); a4.w = f2bf(f0[rq * 4 + 3]);
      *(ushort4*)(op + rq * 8 + hi * 4) = a4;
      b4.x = f2bf(f1[rq * 4 + 0]); b4.y = f2bf(f1[rq * 4 + 1]);
      b4.z = f2bf(f1[rq * 4 + 2]); b4.w = f2bf(f1[rq * 4 + 3]);
      *(ushort4*)(op + 32 + rq * 8 + hi * 4) = b4;
    }
  }
}

// ---------------------------------------------------------------------------
// Launch
// ---------------------------------------------------------------------------
extern "C" void kernel_launch(void* const* d_in, const int* in_sizes, int n_in,
                              void* d_out, int out_size, void* d_ws, size_t ws_size,
                              hipStream_t stream) {
  const float* x     = (const float*)d_in[0];
  const float* ln1_w = (const float*)d_in[1];
  const float* ln1_b = (const float*)d_in[2];
  const float* wq    = (const float*)d_in[3];
  const float* bq    = (const float*)d_in[4];
  const float* wk    = (const float*)d_in[5];
  const float* bk    = (const float*)d_in[6];
  const float* wv    = (const float*)d_in[7];
  const float* bv    = (const float*)d_in[8];
  const float* wo    = (const float*)d_in[9];
  const float* bo    = (const float*)d_in[10];
  const float* ln2_w = (const float*)d_in[11];
  const float* ln2_b = (const float*)d_in[12];
  const float* wu    = (const float*)d_in[13];
  const float* bu    = (const float*)d_in[14];
  const float* wd    = (const float*)d_in[15];
  const float* bd    = (const float*)d_in[16];

  char* W = (char*)d_ws;
  const size_t MB = 1ull << 20;
  unsigned short* wqkvT = (unsigned short*)(W + 0 * MB);  // [3072][1024]
  unsigned short* woT   = (unsigned short*)(W + 6 * MB);  // [1024][1024] (contiguous after wqkvT)
  unsigned short* wuT   = (unsigned short*)(W + 8 * MB);  // [4096][1024]
  unsigned short* wdT   = (unsigned short*)(W + 16 * MB); // [1024][4096]
  unsigned short* xn    = (unsigned short*)(W + 24 * MB); // [4096][1024]
  unsigned short* qb    = (unsigned short*)(W + 32 * MB); // [32][2048][64]
  unsigned short* kb    = (unsigned short*)(W + 40 * MB);
  unsigned short* vb    = (unsigned short*)(W + 48 * MB); // [32][64][2048] kv-permuted
  unsigned short* cx    = (unsigned short*)(W + 56 * MB); // vnat -> ctx -> hn
  float*          hid   = (float*)(W + 64 * MB);          // [4096][1024] fp32
  unsigned short* up    = (unsigned short*)(W + 24 * MB); // [4096][4096] (reuse)

  const dim3 tb(32, 8);
  // --- weight prep (bf16, transposed) ---
  transpose_cast4<<<dim3(32, 32, 4), tb, 0, stream>>>(wq, wk, wv, wo, wqkvT);
  transpose_cast<<<dim3(128, 32), tb, 0, stream>>>(wu, wuT, 1024, 4096);
  transpose_cast<<<dim3(32, 128), tb, 0, stream>>>(wd, wdT, 4096, 1024);

  // --- attention block ---
  layernorm_kernel<<<4096, 256, 0, stream>>>(x, ln1_w, ln1_b, xn);
  gemm_bt_2b<0><<<dim3(24, 32), 256, 0, stream>>>(
      xn, wqkvT, bq, qb, nullptr, 1024, kb, cx, bk, bv);
  transpose_bf16<<<dim3(2, 64, 32), tb, 0, stream>>>(cx, vb, 2048, 64);
  flash_attn<<<dim3(32, 32), 256, 0, stream>>>(qb, kb, vb, cx);
  gemm_bt_p3<<<dim3(16, 32), 256, 0, stream>>>(
      cx, woT, bo, hid, x, 1024);

  // --- FFN block ---
  layernorm_kernel<<<4096, 256, 0, stream>>>(hid, ln2_w, ln2_b, cx);
  gemm_bt_2b<2><<<dim3(32, 32), 256, 0, stream>>>(
      cx, wuT, bu, up, nullptr, 1024, nullptr, nullptr, nullptr, nullptr);
  gemm_bt_p3<<<dim3(16, 32), 256, 0, stream>>>(
      up, wdT, bd, (float*)d_out, hid, 4096);
}